// Round 5
// baseline (25.461 us; speedup 1.0000x reference)
//
#include <hip/hip_runtime.h>

// out[b,e,t] = v[t] * P[b,e,t] + bias[t],  P[t] = r*P[t-1] + x[t],  r = clip(d,0.9,1)^(1/c)
// One 64-lane wave per (b,e) row of length S=2048, chunked ownership:
// row = 8 chunks x 256 floats; in chunk c, lane L owns floats [c*256+4L, +4).
// R5: persistent waves (512 blocks x 4 waves, 4 rows each, grid-stride),
// weight/bias register-resident per wave, 1-deep software-pipelined x loads
// so the VMEM queue stays fed during the scan/shuffle compute phase.

#define DECAY_CONSTANT 1.0f

__device__ __forceinline__ float readlane_f(float v, int l) {
    return __uint_as_float(__builtin_amdgcn_readlane(__float_as_uint(v), l));
}

__global__ __launch_bounds__(256) void decay_scan_kernel(
    const float* __restrict__ x,       // (nrows, S)
    const float* __restrict__ weight,  // (S,)
    const float* __restrict__ bias,    // (S,)
    const float* __restrict__ decay,   // (1,)
    float* __restrict__ out,           // (nrows, S)
    int nrows)
{
    constexpr int S  = 2048;
    constexpr int NC = 8;    // chunks per row
    constexpr int CW = 256;  // floats per chunk
    constexpr int RPW = 4;   // rows per wave

    const int lane   = threadIdx.x & 63;
    const int wave   = threadIdx.x >> 6;
    const int gw     = blockIdx.x * 4 + wave;   // global wave id
    const int nwaves = gridDim.x * 4;

    float d = decay[0];
    d = fminf(fmaxf(d, 0.9f), 1.0f);
    const float r = (DECAY_CONSTANT == 1.0f) ? d : powf(d, 1.0f / DECAY_CONSTANT);

    // wave-uniform powers of r
    const float r2 = r * r;
    const float r3 = r2 * r;
    const float r4 = r2 * r2;
    const float r8   = r4 * r4;
    const float r16  = r8 * r8;
    const float r32  = r16 * r16;
    const float r64  = r32 * r32;
    const float r128 = r64 * r64;
    const float r256 = r128 * r128;

    // per-lane r^(4L): exact binary exponentiation from wave-uniform powers
    float r4L = 1.0f;
    r4L *= (lane & 1)  ? r4   : 1.0f;
    r4L *= (lane & 2)  ? r8   : 1.0f;
    r4L *= (lane & 4)  ? r16  : 1.0f;
    r4L *= (lane & 8)  ? r32  : 1.0f;
    r4L *= (lane & 16) ? r64  : 1.0f;
    r4L *= (lane & 32) ? r128 : 1.0f;

    const int off4 = lane * 4;

    // ---- weight/bias register-resident for all rows this wave handles ----
    float4 w[NC], bb[NC];
    #pragma unroll
    for (int c = 0; c < NC; ++c) {
        w[c]  = *reinterpret_cast<const float4*>(weight + c * CW + off4);
        bb[c] = *reinterpret_cast<const float4*>(bias   + c * CW + off4);
    }

    // ---- software-pipelined row loop ----
    float4 pc[NC], pn[NC];

    {   // prologue: load first row
        const int row0 = gw;
        if (row0 < nrows) {
            const float* xr = x + (size_t)row0 * S;
            #pragma unroll
            for (int c = 0; c < NC; ++c)
                pc[c] = *reinterpret_cast<const float4*>(xr + c * CW + off4);
        }
    }

    #pragma unroll
    for (int it = 0; it < RPW; ++it) {
        const int row = gw + nwaves * it;
        if (row >= nrows) break;

        // prefetch next row before computing current
        const int nrow = row + nwaves;
        if (it + 1 < RPW && nrow < nrows) {
            const float* xr = x + (size_t)nrow * S;
            #pragma unroll
            for (int c = 0; c < NC; ++c)
                pn[c] = *reinterpret_cast<const float4*>(xr + c * CW + off4);
        }

        // ---- per-lane local scans (independent across chunks) ----
        float4 p[NC];
        #pragma unroll
        for (int c = 0; c < NC; ++c) {
            p[c].x = pc[c].x;
            p[c].y = fmaf(r, p[c].x, pc[c].y);
            p[c].z = fmaf(r, p[c].y, pc[c].z);
            p[c].w = fmaf(r, p[c].z, pc[c].w);
        }

        // ---- 8 independent wave-scans of segment sums (1 shuffle/step) ----
        float b[NC];
        #pragma unroll
        for (int c = 0; c < NC; ++c) b[c] = p[c].w;

        #pragma unroll
        for (int s = 0; s < 6; ++s) {
            const int off = 1 << s;
            const float m = (s == 0) ? r4 : (s == 1) ? r8 : (s == 2) ? r16
                          : (s == 3) ? r32 : (s == 4) ? r64 : r128;
            #pragma unroll
            for (int c = 0; c < NC; ++c) {
                float up = __shfl_up(b[c], off);
                if (lane >= off) b[c] = fmaf(m, up, b[c]);
            }
        }

        // ---- per-chunk carry-in from previous lane, chunk totals ----
        float t[NC], Tc[NC];
        #pragma unroll
        for (int c = 0; c < NC; ++c) {
            float bp = __shfl_up(b[c], 1);
            if (lane == 0) bp = 0.0f;
            t[c]  = bp;
            Tc[c] = readlane_f(b[c], 63);
        }

        // ---- scalar cross-chunk carry chain ----
        float C = 0.0f;
        #pragma unroll
        for (int c = 0; c < NC; ++c) {
            t[c] = fmaf(C, r4L, t[c]);
            C = fmaf(r256, C, Tc[c]);
        }

        // ---- apply, scale by weight, add bias, contiguous stores ----
        float* orow = out + (size_t)row * S;
        #pragma unroll
        for (int c = 0; c < NC; ++c) {
            float P0 = fmaf(r,  t[c], p[c].x);
            float P1 = fmaf(r2, t[c], p[c].y);
            float P2 = fmaf(r3, t[c], p[c].z);
            float P3 = fmaf(r4, t[c], p[c].w);
            float4 o;
            o.x = fmaf(w[c].x, P0, bb[c].x);
            o.y = fmaf(w[c].y, P1, bb[c].y);
            o.z = fmaf(w[c].z, P2, bb[c].z);
            o.w = fmaf(w[c].w, P3, bb[c].w);
            *reinterpret_cast<float4*>(orow + c * CW + off4) = o;
        }

        // rotate pipeline registers (SSA-renamed under full unroll)
        #pragma unroll
        for (int c = 0; c < NC; ++c) pc[c] = pn[c];
    }
}

extern "C" void kernel_launch(void* const* d_in, const int* in_sizes, int n_in,
                              void* d_out, int out_size, void* d_ws, size_t ws_size,
                              hipStream_t stream) {
    const float* x      = (const float*)d_in[0];  // (B, E, S) fp32
    const float* weight = (const float*)d_in[1];  // (1, S)
    const float* bias   = (const float*)d_in[2];  // (S,)
    const float* decay  = (const float*)d_in[3];  // (1,)
    float* out = (float*)d_out;

    const int S = in_sizes[1];          // 2048
    const int nrows = in_sizes[0] / S;  // B*E = 8192

    const int nwaves = (nrows + 3) / 4;           // 4 rows per wave
    const int blocks = (nwaves + 3) / 4;          // 4 waves per block (512)
    decay_scan_kernel<<<blocks, 256, 0, stream>>>(x, weight, bias, decay, out, nrows);
}